// Round 8
// baseline (204.319 us; speedup 1.0000x reference)
//
#include <hip/hip_runtime.h>
#include <cstddef>

#define EPSF 1e-6f

constexpr int D   = 1024;
constexpr int Bv  = 2;
constexpr int S   = 2048;
constexpr int M   = Bv * S;    // 4096
constexpr int CH  = 256;       // chunk
constexpr int NCH = S / CH;    // 8

constexpr int TSZ  = 128 * 32; // 128-row LDS tile (elems, 8 KB)
constexpr int T66  = 64 * 64;  // 64x64 BK=64 LDS tile (elems, 8 KB)

typedef __attribute__((ext_vector_type(8))) short short8;   // 8 bf16
typedef __attribute__((ext_vector_type(4))) float floatx4;  // 4 fp32

__device__ __forceinline__ float elu1(float x) { return x > 0.f ? x + 1.f : __expf(x); }
__device__ __forceinline__ float sigmoidf_(float x) { return 1.f / (1.f + __expf(-x)); }
__device__ __forceinline__ unsigned short f2bf(float x) {
    unsigned u = __float_as_uint(x);
    return (unsigned short)((u + 0x7fffu + ((u >> 16) & 1u)) >> 16);
}
__device__ __forceinline__ float bf2f(unsigned short h) {
    return __uint_as_float(((unsigned)h) << 16);
}
__device__ __forceinline__ float wave_reduce(float x) {
#pragma unroll
    for (int off = 32; off > 0; off >>= 1) x += __shfl_down(x, off);
    return x;
}

// async global->LDS, 16B per lane (dest = wave-uniform base + lane*16)
__device__ __forceinline__ void gl_lds16(const unsigned short* g, unsigned short* l) {
    __builtin_amdgcn_global_load_lds(
        (const __attribute__((address_space(1))) void*)g,
        (__attribute__((address_space(3))) void*)l, 16, 0, 0);
}

// ---- r2-verified 128x32 staging (both-sides XOR swizzle, conflicts->0) ----
__device__ __forceinline__ void stage128x32(const unsigned short* g, int stride,
                                            unsigned short* lds, int wave, int lane) {
    const int t   = (wave << 6) + lane;
    const int row = t >> 2;
    const int cb  = (((t & 3) ^ ((row >> 1) & 3)) << 3);
    unsigned short* l0 = lds + (wave << 9);
    gl_lds16(g + (size_t)row * stride + cb, l0);
    gl_lds16(g + (size_t)(row + 64) * stride + cb, l0 + 2048);
}

// r1-verified BK=64 64-row staging (pv/outproj path)
__device__ __forceinline__ void stage64x64(const unsigned short* g, int stride,
                                           unsigned short* lds, int wave, int lane) {
    const int base = (wave << 6) + lane;
    const int c8   = (lane & 7) ^ (lane >> 3);
#pragma unroll
    for (int q = 0; q < 2; ++q) {
        const int P   = (q << 8) + base;
        const int row = P >> 3;
        gl_lds16(g + (size_t)row * stride + (c8 << 3), lds + (q << 11) + (wave << 9));
    }
}

// r2-verified 16-MFMA step, 128x128 tile, wave quadrant (wm,wn in {0,64})
__device__ __forceinline__ void mfma_step(const unsigned short* As, const unsigned short* Bs,
                                          int wm, int wn, int fr, int g, floatx4 acc[4][4]) {
    const int off = ((g ^ ((fr >> 1) & 3)) << 3);
    short8 af[4], bf[4];
#pragma unroll
    for (int i = 0; i < 4; ++i) af[i] = *(const short8*)&As[(wm + i * 16 + fr) * 32 + off];
#pragma unroll
    for (int j = 0; j < 4; ++j) bf[j] = *(const short8*)&Bs[(wn + j * 16 + fr) * 32 + off];
#pragma unroll
    for (int i = 0; i < 4; ++i)
#pragma unroll
        for (int j = 0; j < 4; ++j)
            acc[i][j] = __builtin_amdgcn_mfma_f32_16x16x32_bf16(af[i], bf[j], acc[i][j], 0, 0, 0);
}

// ==================== r8: triple-buffered counted-vmcnt 128² loop ====================
// Per K-tile: ONE s_waitcnt vmcnt(4) (tile u+1's 4 loads stay in flight; 0 only at
// the last tile) + ONE raw s_barrier + stage tile u+2 into buf[(u+2)%3] + 16 MFMA.
// 48 KB LDS -> 3 blocks/CU; replaces the __syncthreads full-drain (m97 disease).
// Hazards: barrier publishes all threads' tile-u loads (each thread vmcnt's its own
// first); WAR on buf[(u+2)%3]==(u-1)%3 is safe (tile u-1 ds_reads complete before its
// MFMAs, hence before this barrier). Empty asm pins ds_reads below the barrier.
__device__ __forceinline__ void gemm_loop_tb(const unsigned short* __restrict__ Ag,
                                             const unsigned short* __restrict__ Bg,
                                             unsigned short* As, unsigned short* Bs,
                                             int wave, int lane, int wm, int wn, int fr, int g,
                                             floatx4 acc[4][4]) {
    const int NT = D / 32;   // 32 K-tiles
    stage128x32(Ag, D, As, wave, lane);
    stage128x32(Bg, D, Bs, wave, lane);
    stage128x32(Ag + 32, D, As + TSZ, wave, lane);
    stage128x32(Bg + 32, D, Bs + TSZ, wave, lane);
    int cb = 0;
    for (int u = 0; u < NT; ++u) {
        if (u == NT - 1) asm volatile("s_waitcnt vmcnt(0)" ::: "memory");
        else             asm volatile("s_waitcnt vmcnt(4)" ::: "memory");
        __builtin_amdgcn_s_barrier();
        asm volatile("" ::: "memory");          // keep ds_reads below the barrier
        if (u + 2 < NT) {
            int nb = cb + 2; if (nb >= 3) nb -= 3;
            stage128x32(Ag + (u + 2) * 32, D, As + nb * TSZ, wave, lane);
            stage128x32(Bg + (u + 2) * 32, D, Bs + nb * TSZ, wave, lane);
        }
        __builtin_amdgcn_s_setprio(1);
        mfma_step(As + cb * TSZ, Bs + cb * TSZ, wm, wn, fr, g, acc);
        __builtin_amdgcn_s_setprio(0);
        if (++cb == 3) cb = 0;
    }
}

// ---- r1/r7-verified 64x64 BK=64 machinery (pv64 / outproj64) ----
__device__ __forceinline__ void mfma_6464d(const unsigned short* As, const unsigned short* Bs,
                                           int wm, int wn, int fr, int g,
                                           floatx4 acc[2][2], floatx4 accd[2], short8 bones) {
    const int x7 = fr & 7;
#pragma unroll
    for (int s = 0; s < 2; ++s) {
        const int off = ((g + 4 * s) ^ x7) << 3;
        short8 af[2], bf[2];
#pragma unroll
        for (int i = 0; i < 2; ++i) af[i] = *(const short8*)&As[(wm + i * 16 + fr) * 64 + off];
#pragma unroll
        for (int j = 0; j < 2; ++j) bf[j] = *(const short8*)&Bs[(wn + j * 16 + fr) * 64 + off];
#pragma unroll
        for (int i = 0; i < 2; ++i) {
#pragma unroll
            for (int j = 0; j < 2; ++j)
                acc[i][j] = __builtin_amdgcn_mfma_f32_16x16x32_bf16(af[i], bf[j], acc[i][j], 0, 0, 0);
            accd[i] = __builtin_amdgcn_mfma_f32_16x16x32_bf16(af[i], bones, accd[i], 0, 0, 0);
        }
    }
}

__device__ __forceinline__ void mfma_6464(const unsigned short* As, const unsigned short* Bs,
                                          int wm, int wn, int fr, int g, floatx4 acc[2][2]) {
    const int x7 = fr & 7;
#pragma unroll
    for (int s = 0; s < 2; ++s) {
        const int off = ((g + 4 * s) ^ x7) << 3;
        short8 af[2], bf[2];
#pragma unroll
        for (int i = 0; i < 2; ++i) af[i] = *(const short8*)&As[(wm + i * 16 + fr) * 64 + off];
#pragma unroll
        for (int j = 0; j < 2; ++j) bf[j] = *(const short8*)&Bs[(wn + j * 16 + fr) * 64 + off];
#pragma unroll
        for (int i = 0; i < 2; ++i)
#pragma unroll
            for (int j = 0; j < 2; ++j)
                acc[i][j] = __builtin_amdgcn_mfma_f32_16x16x32_bf16(af[i], bf[j], acc[i][j], 0, 0, 0);
    }
}

__device__ __forceinline__ void gemm_loop_6464d(const unsigned short* Ag, int sA,
                                                const unsigned short* Bg, int sB, int Kk,
                                                unsigned short* As, unsigned short* Bs,
                                                int wave, int lane, int wm, int wn, int fr, int g,
                                                floatx4 acc[2][2], floatx4 accd[2], short8 bones) {
    __syncthreads();
    stage64x64(Ag, sA, As, wave, lane);
    stage64x64(Bg, sB, Bs, wave, lane);
    int buf = 0;
    for (int k0 = 64; k0 < Kk; k0 += 64) {
        __syncthreads();
        const int nb = buf ^ 1;
        stage64x64(Ag + k0, sA, As + nb * T66, wave, lane);
        stage64x64(Bg + k0, sB, Bs + nb * T66, wave, lane);
        mfma_6464d(As + buf * T66, Bs + buf * T66, wm, wn, fr, g, acc, accd, bones);
        buf = nb;
    }
    __syncthreads();
    mfma_6464d(As + buf * T66, Bs + buf * T66, wm, wn, fr, g, acc, accd, bones);
}

__device__ __forceinline__ void gemm_loop_6464(const unsigned short* Ag, int sA,
                                               const unsigned short* Bg, int sB, int Kk,
                                               unsigned short* As, unsigned short* Bs,
                                               int wave, int lane, int wm, int wn, int fr, int g,
                                               floatx4 acc[2][2]) {
    __syncthreads();
    stage64x64(Ag, sA, As, wave, lane);
    stage64x64(Bg, sB, Bs, wave, lane);
    int buf = 0;
    for (int k0 = 64; k0 < Kk; k0 += 64) {
        __syncthreads();
        const int nb = buf ^ 1;
        stage64x64(Ag + k0, sA, As + nb * T66, wave, lane);
        stage64x64(Bg + k0, sB, Bs + nb * T66, wave, lane);
        mfma_6464(As + buf * T66, Bs + buf * T66, wm, wn, fr, g, acc);
        buf = nb;
    }
    __syncthreads();
    mfma_6464(As + buf * T66, Bs + buf * T66, wm, wn, fr, g, acc);
}

// ---------------- prep: cvt h + cvt 4 weights + transpose memory ----------------
__global__ __launch_bounds__(256) void prep(const float* __restrict__ h,
                                            const float* __restrict__ w_q, const float* __restrict__ w_k,
                                            const float* __restrict__ w_v, const float* __restrict__ w_o,
                                            const float* __restrict__ memory,
                                            unsigned short* __restrict__ h_b,
                                            unsigned short* __restrict__ wq_b, unsigned short* __restrict__ wk_b,
                                            unsigned short* __restrict__ wv_b, unsigned short* __restrict__ wo_b,
                                            unsigned short* __restrict__ memT)
{
    __shared__ unsigned short T[64][72];
    const int id = blockIdx.x, tid = threadIdx.x;
    if (id < 4096) {
        const size_t i = ((size_t)id * 256 + tid) * 4;
        float4 v = *(const float4*)(h + i);
        ushort4 o; o.x = f2bf(v.x); o.y = f2bf(v.y); o.z = f2bf(v.z); o.w = f2bf(v.w);
        *(ushort4*)(h_b + i) = o;
    } else if (id < 8192) {
        const int t = id - 4096, which = t >> 10;
        const float* in = (which == 0) ? w_q : (which == 1) ? w_k : (which == 2) ? w_v : w_o;
        unsigned short* out = (which == 0) ? wq_b : (which == 1) ? wk_b : (which == 2) ? wv_b : wo_b;
        const size_t i = ((size_t)(t & 1023) * 256 + tid) * 4;
        float4 v = *(const float4*)(in + i);
        ushort4 o; o.x = f2bf(v.x); o.y = f2bf(v.y); o.z = f2bf(v.z); o.w = f2bf(v.w);
        *(ushort4*)(out + i) = o;
    } else {
        const int t = id - 8192;
        const int d0 = (t >> 4) * 64, e0 = (t & 15) * 64;
        const int r = tid >> 4, c4 = (tid & 15) * 4;
        for (int rr = r; rr < 64; rr += 16) {
            float4 v = *(const float4*)(memory + (size_t)(d0 + rr) * D + e0 + c4);
            T[rr][c4 + 0] = f2bf(v.x); T[rr][c4 + 1] = f2bf(v.y);
            T[rr][c4 + 2] = f2bf(v.z); T[rr][c4 + 3] = f2bf(v.w);
        }
        __syncthreads();
        for (int rr = r; rr < 64; rr += 16) {
            ushort4 o;
            o.x = T[c4 + 0][rr]; o.y = T[c4 + 1][rr];
            o.z = T[c4 + 2][rr]; o.w = T[c4 + 3][rr];
            *(ushort4*)(memT + (size_t)(e0 + rr) * D + d0 + c4) = o;
        }
    }
}

// ---------------- proj3: q/k/v projections, 128² tiles, triple-buffered counted-vmcnt ----------
__global__ __launch_bounds__(256) void proj3(const unsigned short* __restrict__ h_b,
                                             const unsigned short* __restrict__ wq,
                                             const unsigned short* __restrict__ wk,
                                             const unsigned short* __restrict__ wv,
                                             unsigned short* __restrict__ sq,
                                             unsigned short* __restrict__ sk,
                                             unsigned short* __restrict__ v)
{
    __shared__ unsigned short As[3 * TSZ], Bs[3 * TSZ];   // 48 KB -> 3 blocks/CU
    const int id = blockIdx.x;
    const int x = id & 7, y = id >> 3;
    const int strip = x + 8 * (y % 12);
    const int n     = y / 12;
    const int sub = strip >> 5, m = strip & 31;
    const int m0 = m * 128, n0 = n * 128;
    const unsigned short* B = (sub == 0) ? wq : (sub == 1) ? wk : wv;
    unsigned short* C = (sub == 0) ? sq : (sub == 1) ? sk : v;

    const int tid = threadIdx.x, wave = tid >> 6, lane = tid & 63;
    const int wm = (wave >> 1) * 64, wn = (wave & 1) * 64;
    const int fr = lane & 15, g = lane >> 4;
    const int q4 = g * 4;

    floatx4 acc[4][4] = {};
    gemm_loop_tb(h_b + (size_t)m0 * D, B + (size_t)n0 * D,
                 As, Bs, wave, lane, wm, wn, fr, g, acc);

#pragma unroll
    for (int i = 0; i < 4; ++i)
#pragma unroll
        for (int j = 0; j < 4; ++j) {
            const int col = n0 + wn + j * 16 + fr;
#pragma unroll
            for (int r = 0; r < 4; ++r) {
                const int row = m0 + wm + i * 16 + q4 + r;
                float val = acc[i][j][r];
                if (sub < 2) val = elu1(val);
                C[(size_t)row * D + col] = f2bf(val);
            }
        }
}

// ---------------- stage3: memgemm(256) + scores(288) tb-loop + v-transpose(1024) + rowscale(1024)
__global__ __launch_bounds__(256) void stage3(const unsigned short* __restrict__ sq,
                                              const unsigned short* __restrict__ sk,
                                              const unsigned short* __restrict__ memT,
                                              const unsigned short* __restrict__ v_b,
                                              const float* __restrict__ mnorm,
                                              const float* __restrict__ gate,
                                              unsigned short* __restrict__ combm,
                                              unsigned short* __restrict__ Sbuf2,
                                              unsigned short* __restrict__ vT,
                                              float* __restrict__ rowscale)
{
    __shared__ unsigned short As[3 * TSZ], Bs[3 * TSZ];   // 48 KB
    const int id = blockIdx.x, tid = threadIdx.x;
    const int wave = tid >> 6, lane = tid & 63;
    const int wm = (wave >> 1) * 64, wn = (wave & 1) * 64;
    const int fr = lane & 15, g = lane >> 4;
    const int q4 = g * 4;

    if (id < 256) {
        const int x = id & 7, y = id >> 3;
        const int m0 = (x + 8 * (y & 3)) * 128;
        const int n0 = (y >> 2) * 128;
        floatx4 acc[4][4] = {};
        gemm_loop_tb(sq + (size_t)m0 * D, memT + (size_t)n0 * D,
                     As, Bs, wave, lane, wm, wn, fr, g, acc);
#pragma unroll
        for (int i = 0; i < 4; ++i)
#pragma unroll
            for (int j = 0; j < 4; ++j) {
                const int col = n0 + wn + j * 16 + fr;
#pragma unroll
                for (int r = 0; r < 4; ++r)
                    combm[(size_t)(m0 + wm + i * 16 + q4 + r) * D + col] = f2bf(acc[i][j][r]);
            }
    } else if (id < 544) {
        const int t = id - 256;
        const int b = t / 144, rem = t % 144;
        const int p = rem >> 2, tt = rem & 3;
        const int it = tt >> 1, jt = tt & 1;
        int c = 0;
        while ((c + 1) * (c + 2) / 2 <= p) ++c;
        const int j = p - c * (c + 1) / 2;
        unsigned short* Srow0 = Sbuf2 + (size_t)(b * NCH + c) * CH * S;

        if (j == c && jt > it) {  // fully above diagonal: zero-fill
            const int row = it * 128 + (tid >> 1);
            unsigned short* zp = Srow0 + (size_t)row * S + j * CH + jt * 128 + (tid & 1) * 64;
            uint4 z4 = make_uint4(0, 0, 0, 0);
#pragma unroll
            for (int i = 0; i < 8; ++i) *(uint4*)(zp + i * 8) = z4;
            return;
        }
        floatx4 acc[4][4] = {};
        gemm_loop_tb(sq + ((size_t)b * S + (size_t)c * CH + it * 128) * D,
                     sk + ((size_t)b * S + (size_t)j * CH + jt * 128) * D,
                     As, Bs, wave, lane, wm, wn, fr, g, acc);
        const bool diag = (j == c && it == jt);
#pragma unroll
        for (int i = 0; i < 4; ++i)
#pragma unroll
            for (int jj = 0; jj < 4; ++jj) {
                const int col = jt * 128 + wn + jj * 16 + fr;
#pragma unroll
                for (int r = 0; r < 4; ++r) {
                    const int row = it * 128 + wm + i * 16 + q4 + r;
                    float val = acc[i][jj][r];
                    if (diag && col > row) val = 0.f;
                    Srow0[(size_t)row * S + j * CH + col] = f2bf(val);
                }
            }
    } else if (id < 1568) {
        unsigned short (*T)[72] = (unsigned short(*)[72])As;
        const int t = id - 544;
        const int b = t >> 9, rem = t & 511;
        const int s0 = (rem >> 4) * 64, d0 = (rem & 15) * 64;
        const int r = tid >> 4, c4 = (tid & 15) * 4;
        const unsigned short* ip = v_b + (size_t)b * S * D;
        for (int rr = r; rr < 64; rr += 16) {
            ushort4 vv = *(const ushort4*)(ip + (size_t)(s0 + rr) * D + d0 + c4);
            T[rr][c4 + 0] = vv.x; T[rr][c4 + 1] = vv.y; T[rr][c4 + 2] = vv.z; T[rr][c4 + 3] = vv.w;
        }
        __syncthreads();
        unsigned short* op = vT + (size_t)b * D * S;
        for (int rr = r; rr < 64; rr += 16) {
            ushort4 o;
            o.x = T[c4 + 0][rr]; o.y = T[c4 + 1][rr];
            o.z = T[c4 + 2][rr]; o.w = T[c4 + 3][rr];
            *(ushort4*)(op + (size_t)(d0 + rr) * S + s0 + c4) = o;
        }
    } else {
        const int row = (id - 1568) * 4 + wave;
        const unsigned short* sr = sq + (size_t)row * D;
        float dot = 0.f, msum = 0.f;
#pragma unroll
        for (int p = 0; p < 2; ++p) {
            const int d0 = p * 512 + lane * 8;
            short8 sv = *(const short8*)(sr + d0);
            float4 m0 = *(const float4*)(mnorm + d0);
            float4 m1 = *(const float4*)(mnorm + d0 + 4);
            dot += bf2f((unsigned short)sv[0]) * m0.x + bf2f((unsigned short)sv[1]) * m0.y
                 + bf2f((unsigned short)sv[2]) * m0.z + bf2f((unsigned short)sv[3]) * m0.w
                 + bf2f((unsigned short)sv[4]) * m1.x + bf2f((unsigned short)sv[5]) * m1.y
                 + bf2f((unsigned short)sv[6]) * m1.z + bf2f((unsigned short)sv[7]) * m1.w;
            msum += m0.x + m0.y + m0.z + m0.w + m1.x + m1.y + m1.z + m1.w;
        }
        dot = wave_reduce(dot);
        msum = wave_reduce(msum);
        if (lane == 0) {
            const float gg = sigmoidf_(gate[0]);
            const float active = (msum >= EPSF) ? 1.f : 0.f;
            rowscale[row] = gg * active / fmaxf(dot, EPSF);
        }
    }
}

// ---------------- pv: 64x64 tiles, BK=64, grid 1024 (r7-verified) ----------------
__global__ __launch_bounds__(256) void pv64(const unsigned short* __restrict__ Sbuf2,
                                            const unsigned short* __restrict__ vT,
                                            const float* __restrict__ rowscale,
                                            const float* __restrict__ gate,
                                            unsigned short* __restrict__ combm)
{
    __shared__ unsigned short As2[2 * T66], Bs2[2 * T66];   // 32 KB
    const int id = blockIdx.x, tid = threadIdx.x;
    const int wave = tid >> 6, lane = tid & 63;
    const int wm = (wave >> 1) * 32, wn = (wave & 1) * 32;
    const int fr = lane & 15, g = lane >> 4;
    const int q4 = g * 4;

    const int x = id & 7, y = id >> 3;          // y: 0..127
    const int g_ = x + 8 * (y & 7);             // group 0..63 — XCD-colocated
    const int e  = y >> 3;                      // 0..15
    const int b = g_ >> 5;
    const int rem = g_ & 31;
    const int c = (NCH - 1) - (rem >> 2);
    const int i0 = (rem & 3) * 64, e0 = e * 64;

    const short one_bf = (short)0x3F80;
    short8 bones = {one_bf, one_bf, one_bf, one_bf, one_bf, one_bf, one_bf, one_bf};

    floatx4 acc[2][2] = {};
    floatx4 accd[2] = {};
    gemm_loop_6464d(Sbuf2 + ((size_t)(b * NCH + c) * CH + i0) * S, S,
                    vT + (size_t)b * D * S + (size_t)e0 * S, S, (c + 1) * CH,
                    As2, Bs2, wave, lane, wm, wn, fr, g, acc, accd, bones);

    const float gg = sigmoidf_(gate[0]);
    const float wloc = 1.f - gg;
#pragma unroll
    for (int i = 0; i < 2; ++i)
#pragma unroll
        for (int j = 0; j < 2; ++j) {
            const int col = e0 + wn + j * 16 + fr;
#pragma unroll
            for (int r = 0; r < 4; ++r) {
                const int li = i0 + wm + i * 16 + q4 + r;
                const int rg = b * S + c * CH + li;
                const float inv = wloc / fmaxf(accd[i][r], EPSF);
                const size_t idx = (size_t)rg * D + col;
                combm[idx] = f2bf(bf2f(combm[idx]) * rowscale[rg] + acc[i][j][r] * inv);
            }
        }
}

// ---------------- out-proj: 64x64 tiles, BK=64, grid 1024 (r7-verified) ----------------
__global__ __launch_bounds__(256) void outproj64(const unsigned short* __restrict__ A,
                                                 const unsigned short* __restrict__ wo,
                                                 float* __restrict__ out)
{
    __shared__ unsigned short As2[2 * T66], Bs2[2 * T66];   // 32 KB
    const int id = blockIdx.x, tid = threadIdx.x;
    const int wave = tid >> 6, lane = tid & 63;
    const int wm = (wave >> 1) * 32, wn = (wave & 1) * 32;
    const int fr = lane & 15, g = lane >> 4;
    const int q4 = g * 4;

    const int x = id & 7, y = id >> 3;          // y: 0..127
    const int m0 = (x + 8 * (y & 7)) * 64;      // strip 0..63 — XCD-colocated
    const int n0 = (y >> 3) * 64;               // 0..15

    floatx4 acc[2][2] = {};
    gemm_loop_6464(A + (size_t)m0 * D, D, wo + (size_t)n0 * D, D, D,
                   As2, Bs2, wave, lane, wm, wn, fr, g, acc);

#pragma unroll
    for (int i = 0; i < 2; ++i)
#pragma unroll
        for (int j = 0; j < 2; ++j) {
            const int col = n0 + wn + j * 16 + fr;
#pragma unroll
            for (int r = 0; r < 4; ++r)
                out[(size_t)(m0 + wm + i * 16 + q4 + r) * D + col] = acc[i][j][r];
        }
}

extern "C" void kernel_launch(void* const* d_in, const int* in_sizes, int n_in,
                              void* d_out, int out_size, void* d_ws, size_t ws_size,
                              hipStream_t stream)
{
    const float* h      = (const float*)d_in[0];
    const float* w_q    = (const float*)d_in[1];
    const float* w_k    = (const float*)d_in[2];
    const float* w_v    = (const float*)d_in[3];
    const float* w_o    = (const float*)d_in[4];
    const float* gate   = (const float*)d_in[5];
    const float* memory = (const float*)d_in[6];
    const float* mnorm  = (const float*)d_in[7];
    float* out = (float*)d_out;

    unsigned short* h_b   = (unsigned short*)d_ws;               // M*D (8 MB)
    unsigned short* wq_b  = h_b + (size_t)M * D;                 // D*D
    unsigned short* wk_b  = wq_b + (size_t)D * D;                // D*D
    unsigned short* wv_b  = wk_b + (size_t)D * D;                // D*D
    unsigned short* wo_b  = wv_b + (size_t)D * D;                // D*D
    unsigned short* memT  = wo_b + (size_t)D * D;                // D*D (2 MB)
    unsigned short* sq_b  = memT + (size_t)D * D;                // M*D (8 MB)
    unsigned short* sk_b  = sq_b + (size_t)M * D;                // M*D (8 MB)
    unsigned short* v_b   = sk_b + (size_t)M * D;                // M*D (8 MB)
    unsigned short* vT    = v_b + (size_t)M * D;                 // M*D (8 MB)
    unsigned short* Sbuf2 = vT + (size_t)M * D;                  // Bv*NCH*CH*S (16.8 MB)
    unsigned short* combm = Sbuf2 + (size_t)Bv * NCH * CH * S;   // M*D (8 MB)
    float* rowscale = (float*)(combm + (size_t)M * D);           // M fp32

    dim3 blk(256);

    prep<<<8448, blk, 0, stream>>>(h, w_q, w_k, w_v, w_o, memory,
                                   h_b, wq_b, wk_b, wv_b, wo_b, memT);
    proj3<<<768, blk, 0, stream>>>(h_b, wq_b, wk_b, wv_b, sq_b, sk_b, v_b);
    stage3<<<2592, blk, 0, stream>>>(sq_b, sk_b, memT, v_b, mnorm, gate,
                                     combm, Sbuf2, vT, rowscale);
    pv64<<<1024, blk, 0, stream>>>(Sbuf2, vT, rowscale, gate, combm);
    outproj64<<<1024, blk, 0, stream>>>(combm, wo_b, out);
}

// Round 9
// 200.473 us; speedup vs baseline: 1.0192x; 1.0192x over previous
//
#include <hip/hip_runtime.h>
#include <cstddef>

#define EPSF 1e-6f

constexpr int D   = 1024;
constexpr int Bv  = 2;
constexpr int S   = 2048;
constexpr int M   = Bv * S;    // 4096
constexpr int CH  = 256;       // chunk
constexpr int NCH = S / CH;    // 8

constexpr int TSZ  = 128 * 32; // 128-row LDS tile (elems, 8 KB)
constexpr int T66  = 64 * 64;  // 64x64 BK=64 LDS tile (elems, 8 KB)

typedef __attribute__((ext_vector_type(8))) short short8;   // 8 bf16
typedef __attribute__((ext_vector_type(4))) float floatx4;  // 4 fp32

__device__ __forceinline__ float elu1(float x) { return x > 0.f ? x + 1.f : __expf(x); }
__device__ __forceinline__ float sigmoidf_(float x) { return 1.f / (1.f + __expf(-x)); }
__device__ __forceinline__ unsigned short f2bf(float x) {
    unsigned u = __float_as_uint(x);
    return (unsigned short)((u + 0x7fffu + ((u >> 16) & 1u)) >> 16);
}
__device__ __forceinline__ float bf2f(unsigned short h) {
    return __uint_as_float(((unsigned)h) << 16);
}
__device__ __forceinline__ float wave_reduce(float x) {
#pragma unroll
    for (int off = 32; off > 0; off >>= 1) x += __shfl_down(x, off);
    return x;
}

// async global->LDS, 16B per lane (dest = wave-uniform base + lane*16)
__device__ __forceinline__ void gl_lds16(const unsigned short* g, unsigned short* l) {
    __builtin_amdgcn_global_load_lds(
        (const __attribute__((address_space(1))) void*)g,
        (__attribute__((address_space(3))) void*)l, 16, 0, 0);
}

// ---- r2-verified 128x32 staging (both-sides XOR swizzle, conflicts->0) ----
__device__ __forceinline__ void stage128x32(const unsigned short* g, int stride,
                                            unsigned short* lds, int wave, int lane) {
    const int t   = (wave << 6) + lane;
    const int row = t >> 2;
    const int cb  = (((t & 3) ^ ((row >> 1) & 3)) << 3);
    unsigned short* l0 = lds + (wave << 9);
    gl_lds16(g + (size_t)row * stride + cb, l0);
    gl_lds16(g + (size_t)(row + 64) * stride + cb, l0 + 2048);
}

// r1-verified BK=64 64-row staging (pv/outproj path)
__device__ __forceinline__ void stage64x64(const unsigned short* g, int stride,
                                           unsigned short* lds, int wave, int lane) {
    const int base = (wave << 6) + lane;
    const int c8   = (lane & 7) ^ (lane >> 3);
#pragma unroll
    for (int q = 0; q < 2; ++q) {
        const int P   = (q << 8) + base;
        const int row = P >> 3;
        gl_lds16(g + (size_t)row * stride + (c8 << 3), lds + (q << 11) + (wave << 9));
    }
}

// r2-verified 16-MFMA step, 128x128 tile, wave quadrant (wm,wn in {0,64})
__device__ __forceinline__ void mfma_step(const unsigned short* As, const unsigned short* Bs,
                                          int wm, int wn, int fr, int g, floatx4 acc[4][4]) {
    const int off = ((g ^ ((fr >> 1) & 3)) << 3);
    short8 af[4], bf[4];
#pragma unroll
    for (int i = 0; i < 4; ++i) af[i] = *(const short8*)&As[(wm + i * 16 + fr) * 32 + off];
#pragma unroll
    for (int j = 0; j < 4; ++j) bf[j] = *(const short8*)&Bs[(wn + j * 16 + fr) * 32 + off];
#pragma unroll
    for (int i = 0; i < 4; ++i)
#pragma unroll
        for (int j = 0; j < 4; ++j)
            acc[i][j] = __builtin_amdgcn_mfma_f32_16x16x32_bf16(af[i], bf[j], acc[i][j], 0, 0, 0);
}

// ==================== r8-verified: triple-buffered counted-vmcnt 128² loop ====================
__device__ __forceinline__ void gemm_loop_tb(const unsigned short* __restrict__ Ag,
                                             const unsigned short* __restrict__ Bg,
                                             unsigned short* As, unsigned short* Bs,
                                             int wave, int lane, int wm, int wn, int fr, int g,
                                             floatx4 acc[4][4]) {
    const int NT = D / 32;   // 32 K-tiles
    stage128x32(Ag, D, As, wave, lane);
    stage128x32(Bg, D, Bs, wave, lane);
    stage128x32(Ag + 32, D, As + TSZ, wave, lane);
    stage128x32(Bg + 32, D, Bs + TSZ, wave, lane);
    int cb = 0;
    for (int u = 0; u < NT; ++u) {
        if (u == NT - 1) asm volatile("s_waitcnt vmcnt(0)" ::: "memory");
        else             asm volatile("s_waitcnt vmcnt(4)" ::: "memory");
        __builtin_amdgcn_s_barrier();
        asm volatile("" ::: "memory");          // keep ds_reads below the barrier
        if (u + 2 < NT) {
            int nb = cb + 2; if (nb >= 3) nb -= 3;
            stage128x32(Ag + (u + 2) * 32, D, As + nb * TSZ, wave, lane);
            stage128x32(Bg + (u + 2) * 32, D, Bs + nb * TSZ, wave, lane);
        }
        __builtin_amdgcn_s_setprio(1);
        mfma_step(As + cb * TSZ, Bs + cb * TSZ, wm, wn, fr, g, acc);
        __builtin_amdgcn_s_setprio(0);
        if (++cb == 3) cb = 0;
    }
}

// ---- r1/r7-verified 64x64 BK=64 machinery (pv64 / outproj64) ----
__device__ __forceinline__ void mfma_6464d(const unsigned short* As, const unsigned short* Bs,
                                           int wm, int wn, int fr, int g,
                                           floatx4 acc[2][2], floatx4 accd[2], short8 bones) {
    const int x7 = fr & 7;
#pragma unroll
    for (int s = 0; s < 2; ++s) {
        const int off = ((g + 4 * s) ^ x7) << 3;
        short8 af[2], bf[2];
#pragma unroll
        for (int i = 0; i < 2; ++i) af[i] = *(const short8*)&As[(wm + i * 16 + fr) * 64 + off];
#pragma unroll
        for (int j = 0; j < 2; ++j) bf[j] = *(const short8*)&Bs[(wn + j * 16 + fr) * 64 + off];
#pragma unroll
        for (int i = 0; i < 2; ++i) {
#pragma unroll
            for (int j = 0; j < 2; ++j)
                acc[i][j] = __builtin_amdgcn_mfma_f32_16x16x32_bf16(af[i], bf[j], acc[i][j], 0, 0, 0);
            accd[i] = __builtin_amdgcn_mfma_f32_16x16x32_bf16(af[i], bones, accd[i], 0, 0, 0);
        }
    }
}

__device__ __forceinline__ void mfma_6464(const unsigned short* As, const unsigned short* Bs,
                                          int wm, int wn, int fr, int g, floatx4 acc[2][2]) {
    const int x7 = fr & 7;
#pragma unroll
    for (int s = 0; s < 2; ++s) {
        const int off = ((g + 4 * s) ^ x7) << 3;
        short8 af[2], bf[2];
#pragma unroll
        for (int i = 0; i < 2; ++i) af[i] = *(const short8*)&As[(wm + i * 16 + fr) * 64 + off];
#pragma unroll
        for (int j = 0; j < 2; ++j) bf[j] = *(const short8*)&Bs[(wn + j * 16 + fr) * 64 + off];
#pragma unroll
        for (int i = 0; i < 2; ++i)
#pragma unroll
            for (int j = 0; j < 2; ++j)
                acc[i][j] = __builtin_amdgcn_mfma_f32_16x16x32_bf16(af[i], bf[j], acc[i][j], 0, 0, 0);
    }
}

__device__ __forceinline__ void gemm_loop_6464d(const unsigned short* Ag, int sA,
                                                const unsigned short* Bg, int sB, int Kk,
                                                unsigned short* As, unsigned short* Bs,
                                                int wave, int lane, int wm, int wn, int fr, int g,
                                                floatx4 acc[2][2], floatx4 accd[2], short8 bones) {
    __syncthreads();
    stage64x64(Ag, sA, As, wave, lane);
    stage64x64(Bg, sB, Bs, wave, lane);
    int buf = 0;
    for (int k0 = 64; k0 < Kk; k0 += 64) {
        __syncthreads();
        const int nb = buf ^ 1;
        stage64x64(Ag + k0, sA, As + nb * T66, wave, lane);
        stage64x64(Bg + k0, sB, Bs + nb * T66, wave, lane);
        mfma_6464d(As + buf * T66, Bs + buf * T66, wm, wn, fr, g, acc, accd, bones);
        buf = nb;
    }
    __syncthreads();
    mfma_6464d(As + buf * T66, Bs + buf * T66, wm, wn, fr, g, acc, accd, bones);
}

__device__ __forceinline__ void gemm_loop_6464(const unsigned short* Ag, int sA,
                                               const unsigned short* Bg, int sB, int Kk,
                                               unsigned short* As, unsigned short* Bs,
                                               int wave, int lane, int wm, int wn, int fr, int g,
                                               floatx4 acc[2][2]) {
    __syncthreads();
    stage64x64(Ag, sA, As, wave, lane);
    stage64x64(Bg, sB, Bs, wave, lane);
    int buf = 0;
    for (int k0 = 64; k0 < Kk; k0 += 64) {
        __syncthreads();
        const int nb = buf ^ 1;
        stage64x64(Ag + k0, sA, As + nb * T66, wave, lane);
        stage64x64(Bg + k0, sB, Bs + nb * T66, wave, lane);
        mfma_6464(As + buf * T66, Bs + buf * T66, wm, wn, fr, g, acc);
        buf = nb;
    }
    __syncthreads();
    mfma_6464(As + buf * T66, Bs + buf * T66, wm, wn, fr, g, acc);
}

// ---------------- prep: cvt h + cvt 4 weights + transpose memory ----------------
__global__ __launch_bounds__(256) void prep(const float* __restrict__ h,
                                            const float* __restrict__ w_q, const float* __restrict__ w_k,
                                            const float* __restrict__ w_v, const float* __restrict__ w_o,
                                            const float* __restrict__ memory,
                                            unsigned short* __restrict__ h_b,
                                            unsigned short* __restrict__ wq_b, unsigned short* __restrict__ wk_b,
                                            unsigned short* __restrict__ wv_b, unsigned short* __restrict__ wo_b,
                                            unsigned short* __restrict__ memT)
{
    __shared__ unsigned short T[64][72];
    const int id = blockIdx.x, tid = threadIdx.x;
    if (id < 4096) {
        const size_t i = ((size_t)id * 256 + tid) * 4;
        float4 v = *(const float4*)(h + i);
        ushort4 o; o.x = f2bf(v.x); o.y = f2bf(v.y); o.z = f2bf(v.z); o.w = f2bf(v.w);
        *(ushort4*)(h_b + i) = o;
    } else if (id < 8192) {
        const int t = id - 4096, which = t >> 10;
        const float* in = (which == 0) ? w_q : (which == 1) ? w_k : (which == 2) ? w_v : w_o;
        unsigned short* out = (which == 0) ? wq_b : (which == 1) ? wk_b : (which == 2) ? wv_b : wo_b;
        const size_t i = ((size_t)(t & 1023) * 256 + tid) * 4;
        float4 v = *(const float4*)(in + i);
        ushort4 o; o.x = f2bf(v.x); o.y = f2bf(v.y); o.z = f2bf(v.z); o.w = f2bf(v.w);
        *(ushort4*)(out + i) = o;
    } else {
        const int t = id - 8192;
        const int d0 = (t >> 4) * 64, e0 = (t & 15) * 64;
        const int r = tid >> 4, c4 = (tid & 15) * 4;
        for (int rr = r; rr < 64; rr += 16) {
            float4 v = *(const float4*)(memory + (size_t)(d0 + rr) * D + e0 + c4);
            T[rr][c4 + 0] = f2bf(v.x); T[rr][c4 + 1] = f2bf(v.y);
            T[rr][c4 + 2] = f2bf(v.z); T[rr][c4 + 3] = f2bf(v.w);
        }
        __syncthreads();
        for (int rr = r; rr < 64; rr += 16) {
            ushort4 o;
            o.x = T[c4 + 0][rr]; o.y = T[c4 + 1][rr];
            o.z = T[c4 + 2][rr]; o.w = T[c4 + 3][rr];
            *(ushort4*)(memT + (size_t)(e0 + rr) * D + d0 + c4) = o;
        }
    }
}

// ---------------- proj3: q/k/v projections, 128² tiles, tb-loop (r8-verified) ----------
__global__ __launch_bounds__(256) void proj3(const unsigned short* __restrict__ h_b,
                                             const unsigned short* __restrict__ wq,
                                             const unsigned short* __restrict__ wk,
                                             const unsigned short* __restrict__ wv,
                                             unsigned short* __restrict__ sq,
                                             unsigned short* __restrict__ sk,
                                             unsigned short* __restrict__ v)
{
    __shared__ unsigned short As[3 * TSZ], Bs[3 * TSZ];   // 48 KB -> 3 blocks/CU
    const int id = blockIdx.x;
    const int x = id & 7, y = id >> 3;
    const int strip = x + 8 * (y % 12);
    const int n     = y / 12;
    const int sub = strip >> 5, m = strip & 31;
    const int m0 = m * 128, n0 = n * 128;
    const unsigned short* B = (sub == 0) ? wq : (sub == 1) ? wk : wv;
    unsigned short* C = (sub == 0) ? sq : (sub == 1) ? sk : v;

    const int tid = threadIdx.x, wave = tid >> 6, lane = tid & 63;
    const int wm = (wave >> 1) * 64, wn = (wave & 1) * 64;
    const int fr = lane & 15, g = lane >> 4;
    const int q4 = g * 4;

    floatx4 acc[4][4] = {};
    gemm_loop_tb(h_b + (size_t)m0 * D, B + (size_t)n0 * D,
                 As, Bs, wave, lane, wm, wn, fr, g, acc);

#pragma unroll
    for (int i = 0; i < 4; ++i)
#pragma unroll
        for (int j = 0; j < 4; ++j) {
            const int col = n0 + wn + j * 16 + fr;
#pragma unroll
            for (int r = 0; r < 4; ++r) {
                const int row = m0 + wm + i * 16 + q4 + r;
                float val = acc[i][j][r];
                if (sub < 2) val = elu1(val);
                C[(size_t)row * D + col] = f2bf(val);
            }
        }
}

// ---------------- stage3: memgemm(256) + scores(288, r9 XCD-colocated) + light(2048) ----------
__global__ __launch_bounds__(256) void stage3(const unsigned short* __restrict__ sq,
                                              const unsigned short* __restrict__ sk,
                                              const unsigned short* __restrict__ memT,
                                              const unsigned short* __restrict__ v_b,
                                              const float* __restrict__ mnorm,
                                              const float* __restrict__ gate,
                                              unsigned short* __restrict__ combm,
                                              unsigned short* __restrict__ Sbuf2,
                                              unsigned short* __restrict__ vT,
                                              float* __restrict__ rowscale)
{
    __shared__ unsigned short As[3 * TSZ], Bs[3 * TSZ];   // 48 KB
    const int id = blockIdx.x, tid = threadIdx.x;
    const int wave = tid >> 6, lane = tid & 63;
    const int wm = (wave >> 1) * 64, wn = (wave & 1) * 64;
    const int fr = lane & 15, g = lane >> 4;
    const int q4 = g * 4;

    if (id < 256) {
        const int x = id & 7, y = id >> 3;
        const int m0 = (x + 8 * (y & 3)) * 128;
        const int n0 = (y >> 2) * 128;
        floatx4 acc[4][4] = {};
        gemm_loop_tb(sq + (size_t)m0 * D, memT + (size_t)n0 * D,
                     As, Bs, wave, lane, wm, wn, fr, g, acc);
#pragma unroll
        for (int i = 0; i < 4; ++i)
#pragma unroll
            for (int j = 0; j < 4; ++j) {
                const int col = n0 + wn + j * 16 + fr;
#pragma unroll
                for (int r = 0; r < 4; ++r)
                    combm[(size_t)(m0 + wm + i * 16 + q4 + r) * D + col] = f2bf(acc[i][j][r]);
            }
    } else if (id < 544) {
        // r9: XCD-colocation swizzle — 36 consecutive items per XCD slot, so the 4
        // quadrants of each (c,j) pair (and neighboring pairs) share one XCD's L2
        // for their sq/sk 128-row panels (was: quadrants round-robin'd over 4 XCDs).
        const int t0 = id - 256;                    // 0..287, (id-256)&7 tracks XCD
        const int t  = (t0 & 7) * 36 + (t0 >> 3);   // bijective: 288 = 8*36
        const int b = t / 144, rem = t % 144;
        const int p = rem >> 2, tt = rem & 3;
        const int it = tt >> 1, jt = tt & 1;
        int c = 0;
        while ((c + 1) * (c + 2) / 2 <= p) ++c;
        const int j = p - c * (c + 1) / 2;
        unsigned short* Srow0 = Sbuf2 + (size_t)(b * NCH + c) * CH * S;

        if (j == c && jt > it) {  // fully above diagonal: zero-fill
            const int row = it * 128 + (tid >> 1);
            unsigned short* zp = Srow0 + (size_t)row * S + j * CH + jt * 128 + (tid & 1) * 64;
            uint4 z4 = make_uint4(0, 0, 0, 0);
#pragma unroll
            for (int i = 0; i < 8; ++i) *(uint4*)(zp + i * 8) = z4;
            return;
        }
        floatx4 acc[4][4] = {};
        gemm_loop_tb(sq + ((size_t)b * S + (size_t)c * CH + it * 128) * D,
                     sk + ((size_t)b * S + (size_t)j * CH + jt * 128) * D,
                     As, Bs, wave, lane, wm, wn, fr, g, acc);
        const bool diag = (j == c && it == jt);
#pragma unroll
        for (int i = 0; i < 4; ++i)
#pragma unroll
            for (int jj = 0; jj < 4; ++jj) {
                const int col = jt * 128 + wn + jj * 16 + fr;
#pragma unroll
                for (int r = 0; r < 4; ++r) {
                    const int row = it * 128 + wm + i * 16 + q4 + r;
                    float val = acc[i][jj][r];
                    if (diag && col > row) val = 0.f;
                    Srow0[(size_t)row * S + j * CH + col] = f2bf(val);
                }
            }
    } else if (id < 1568) {
        unsigned short (*T)[72] = (unsigned short(*)[72])As;
        const int t = id - 544;
        const int b = t >> 9, rem = t & 511;
        const int s0 = (rem >> 4) * 64, d0 = (rem & 15) * 64;
        const int r = tid >> 4, c4 = (tid & 15) * 4;
        const unsigned short* ip = v_b + (size_t)b * S * D;
        for (int rr = r; rr < 64; rr += 16) {
            ushort4 vv = *(const ushort4*)(ip + (size_t)(s0 + rr) * D + d0 + c4);
            T[rr][c4 + 0] = vv.x; T[rr][c4 + 1] = vv.y; T[rr][c4 + 2] = vv.z; T[rr][c4 + 3] = vv.w;
        }
        __syncthreads();
        unsigned short* op = vT + (size_t)b * D * S;
        for (int rr = r; rr < 64; rr += 16) {
            ushort4 o;
            o.x = T[c4 + 0][rr]; o.y = T[c4 + 1][rr];
            o.z = T[c4 + 2][rr]; o.w = T[c4 + 3][rr];
            *(ushort4*)(op + (size_t)(d0 + rr) * S + s0 + c4) = o;
        }
    } else {
        const int row = (id - 1568) * 4 + wave;
        const unsigned short* sr = sq + (size_t)row * D;
        float dot = 0.f, msum = 0.f;
#pragma unroll
        for (int p = 0; p < 2; ++p) {
            const int d0 = p * 512 + lane * 8;
            short8 sv = *(const short8*)(sr + d0);
            float4 m0 = *(const float4*)(mnorm + d0);
            float4 m1 = *(const float4*)(mnorm + d0 + 4);
            dot += bf2f((unsigned short)sv[0]) * m0.x + bf2f((unsigned short)sv[1]) * m0.y
                 + bf2f((unsigned short)sv[2]) * m0.z + bf2f((unsigned short)sv[3]) * m0.w
                 + bf2f((unsigned short)sv[4]) * m1.x + bf2f((unsigned short)sv[5]) * m1.y
                 + bf2f((unsigned short)sv[6]) * m1.z + bf2f((unsigned short)sv[7]) * m1.w;
            msum += m0.x + m0.y + m0.z + m0.w + m1.x + m1.y + m1.z + m1.w;
        }
        dot = wave_reduce(dot);
        msum = wave_reduce(msum);
        if (lane == 0) {
            const float gg = sigmoidf_(gate[0]);
            const float active = (msum >= EPSF) ? 1.f : 0.f;
            rowscale[row] = gg * active / fmaxf(dot, EPSF);
        }
    }
}

// ---------------- pv: 64x64 tiles, BK=64, grid 1024; r9: exact-zero K-trim ----------------
// Rows i0..i0+63 of chunk c: S cols >= c*CH + i0 + 64 are EXACT zeros (masked diag
// region) -> trim K from (c+1)*CH to c*CH+i0+64. Bit-identical (0*V terms dropped),
// -8.3% of total pv K-steps.
__global__ __launch_bounds__(256) void pv64(const unsigned short* __restrict__ Sbuf2,
                                            const unsigned short* __restrict__ vT,
                                            const float* __restrict__ rowscale,
                                            const float* __restrict__ gate,
                                            unsigned short* __restrict__ combm)
{
    __shared__ unsigned short As2[2 * T66], Bs2[2 * T66];   // 32 KB
    const int id = blockIdx.x, tid = threadIdx.x;
    const int wave = tid >> 6, lane = tid & 63;
    const int wm = (wave >> 1) * 32, wn = (wave & 1) * 32;
    const int fr = lane & 15, g = lane >> 4;
    const int q4 = g * 4;

    const int x = id & 7, y = id >> 3;          // y: 0..127
    const int g_ = x + 8 * (y & 7);             // group 0..63 — XCD-colocated
    const int e  = y >> 3;                      // 0..15
    const int b = g_ >> 5;
    const int rem = g_ & 31;
    const int c = (NCH - 1) - (rem >> 2);
    const int i0 = (rem & 3) * 64, e0 = e * 64;
    const int Kk = c * CH + i0 + 64;            // r9 trim (was (c+1)*CH)

    const short one_bf = (short)0x3F80;
    short8 bones = {one_bf, one_bf, one_bf, one_bf, one_bf, one_bf, one_bf, one_bf};

    floatx4 acc[2][2] = {};
    floatx4 accd[2] = {};
    gemm_loop_6464d(Sbuf2 + ((size_t)(b * NCH + c) * CH + i0) * S, S,
                    vT + (size_t)b * D * S + (size_t)e0 * S, S, Kk,
                    As2, Bs2, wave, lane, wm, wn, fr, g, acc, accd, bones);

    const float gg = sigmoidf_(gate[0]);
    const float wloc = 1.f - gg;
#pragma unroll
    for (int i = 0; i < 2; ++i)
#pragma unroll
        for (int j = 0; j < 2; ++j) {
            const int col = e0 + wn + j * 16 + fr;
#pragma unroll
            for (int r = 0; r < 4; ++r) {
                const int li = i0 + wm + i * 16 + q4 + r;
                const int rg = b * S + c * CH + li;
                const float inv = wloc / fmaxf(accd[i][r], EPSF);
                const size_t idx = (size_t)rg * D + col;
                combm[idx] = f2bf(bf2f(combm[idx]) * rowscale[rg] + acc[i][j][r] * inv);
            }
        }
}

// ---------------- out-proj: 64x64 tiles, BK=64, grid 1024 (r7-verified) ----------------
__global__ __launch_bounds__(256) void outproj64(const unsigned short* __restrict__ A,
                                                 const unsigned short* __restrict__ wo,
                                                 float* __restrict__ out)
{
    __shared__ unsigned short As2[2 * T66], Bs2[2 * T66];   // 32 KB
    const int id = blockIdx.x, tid = threadIdx.x;
    const int wave = tid >> 6, lane = tid & 63;
    const int wm = (wave >> 1) * 32, wn = (wave & 1) * 32;
    const int fr = lane & 15, g = lane >> 4;
    const int q4 = g * 4;

    const int x = id & 7, y = id >> 3;          // y: 0..127
    const int m0 = (x + 8 * (y & 7)) * 64;      // strip 0..63 — XCD-colocated
    const int n0 = (y >> 3) * 64;               // 0..15

    floatx4 acc[2][2] = {};
    gemm_loop_6464(A + (size_t)m0 * D, D, wo + (size_t)n0 * D, D, D,
                   As2, Bs2, wave, lane, wm, wn, fr, g, acc);

#pragma unroll
    for (int i = 0; i < 2; ++i)
#pragma unroll
        for (int j = 0; j < 2; ++j) {
            const int col = n0 + wn + j * 16 + fr;
#pragma unroll
            for (int r = 0; r < 4; ++r)
                out[(size_t)(m0 + wm + i * 16 + q4 + r) * D + col] = acc[i][j][r];
        }
}

extern "C" void kernel_launch(void* const* d_in, const int* in_sizes, int n_in,
                              void* d_out, int out_size, void* d_ws, size_t ws_size,
                              hipStream_t stream)
{
    const float* h      = (const float*)d_in[0];
    const float* w_q    = (const float*)d_in[1];
    const float* w_k    = (const float*)d_in[2];
    const float* w_v    = (const float*)d_in[3];
    const float* w_o    = (const float*)d_in[4];
    const float* gate   = (const float*)d_in[5];
    const float* memory = (const float*)d_in[6];
    const float* mnorm  = (const float*)d_in[7];
    float* out = (float*)d_out;

    unsigned short* h_b   = (unsigned short*)d_ws;               // M*D (8 MB)
    unsigned short* wq_b  = h_b + (size_t)M * D;                 // D*D
    unsigned short* wk_b  = wq_b + (size_t)D * D;                // D*D
    unsigned short* wv_b  = wk_b + (size_t)D * D;                // D*D
    unsigned short* wo_b  = wv_b + (size_t)D * D;                // D*D
    unsigned short* memT  = wo_b + (size_t)D * D;                // D*D (2 MB)
    unsigned short* sq_b  = memT + (size_t)D * D;                // M*D (8 MB)
    unsigned short* sk_b  = sq_b + (size_t)M * D;                // M*D (8 MB)
    unsigned short* v_b   = sk_b + (size_t)M * D;                // M*D (8 MB)
    unsigned short* vT    = v_b + (size_t)M * D;                 // M*D (8 MB)
    unsigned short* Sbuf2 = vT + (size_t)M * D;                  // Bv*NCH*CH*S (16.8 MB)
    unsigned short* combm = Sbuf2 + (size_t)Bv * NCH * CH * S;   // M*D (8 MB)
    float* rowscale = (float*)(combm + (size_t)M * D);           // M fp32

    dim3 blk(256);

    prep<<<8448, blk, 0, stream>>>(h, w_q, w_k, w_v, w_o, memory,
                                   h_b, wq_b, wk_b, wv_b, wo_b, memT);
    proj3<<<768, blk, 0, stream>>>(h_b, wq_b, wk_b, wv_b, sq_b, sk_b, v_b);
    stage3<<<2592, blk, 0, stream>>>(sq_b, sk_b, memT, v_b, mnorm, gate,
                                     combm, Sbuf2, vT, rowscale);
    pv64<<<1024, blk, 0, stream>>>(Sbuf2, vT, rowscale, gate, combm);
    outproj64<<<1024, blk, 0, stream>>>(combm, wo_b, out);
}